// Round 10
// baseline (648.399 us; speedup 1.0000x reference)
//
#include <hip/hip_runtime.h>
#include <hip/hip_bf16.h>
#include <hip/hip_fp8.h>

// LabelWiseAttn: m[b,c,d] = softmax_l(U[c,:]·x[b,l,:]) @ x[b]
// B=16 L=2048 D=512 C=8921.  Flash-style fusion, fp32 accum.
// R25 = R24 G1 (MX K=128, 16B-swizzled XK LDS, b128 reads) + G2 B-operands in
//      REGISTERS (fr[8], T14 phase-ahead prefetch from R22-verified flat xt3
//      layout): removes XT LDS (48KB slots, 1152 cyc reads + 256 cyc DMA).
//      Register budget (R16/R22 calibration: 256/wave @ 2 waves/SIMD):
//      CTn 128->64 (acc 128->64) + us 32 + fr 64 ~ 190. G1 waves l-split
//      (cg=w&3, hf=w>>2, R22 pattern); G2 waves (cq=w>>2, dq=w&3).
//      Phase p: {stage XK(p+1); G1(p); G2(p-1) from fr+P; load fr(p);
//      softmax->P; BARV(8)}. Ledger: XK(2) issued before fr(8) ->
//      vmcnt(8) drains XK(p+1), keeps fr(p) in flight (consumed next phase,
//      full-phase latency cover -- R23's mistake was in-phase consumption).
//      NWGn 2240 -> tail idle 12.5% -> ~3%.

#define Bn 16
#define Ln 2048
#define Dn 512
#define Cn 8921
#define CPn 8960            // C padded to multiple of 64
#define CTn 64              // c-tile per workgroup
#define NCTn (CPn/CTn)      // 140
#define NWGn (Bn*NCTn)      // 2240
#define NP   (Ln/32)        // 64 pairs of 32 l

typedef __attribute__((ext_vector_type(8))) short bf16x8;
typedef __attribute__((ext_vector_type(4))) float f32x4;
typedef __attribute__((ext_vector_type(4))) int i32x4;
typedef __attribute__((ext_vector_type(8))) int i32x8;

// LDS ushort offsets
#define XKu(i) ((i)*8192)              // 2 slots x 16 KB: [32 l][512 B fp8] swz16
#define Pu(i)  (16384 + (i)*3072)      // 2 slots x 6 KB: [2 half][64 c][24]
#define DENu   33792                   // float[2][64] @ byte 67584 (above er)
#define P_S 24
#define LDS_BYTES 68096                // er region 67584 B + den 512 B

#define ER_S 132            // epilogue f32 stride (528 B = 0 mod 16)

__device__ __forceinline__ unsigned short f2bf(float f) {
  unsigned int u = __float_as_uint(f);
  u += 0x7fffu + ((u >> 16) & 1u);      // RNE; no NaN possible here
  return (unsigned short)(u >> 16);
}

__device__ __forceinline__ unsigned int f2fp8(float f) {
  __hip_fp8_e4m3 q(f);                  // OCP e4m3fn, RNE-saturating
  return (unsigned int)q.__x;
}

// async global->LDS, 16B/lane, dest = wave-uniform base + lane*16 (HW)
__device__ __forceinline__ void gload16(const unsigned short* g, unsigned short* l) {
  __builtin_amdgcn_global_load_lds(
      (const __attribute__((address_space(1))) unsigned int*)g,
      (__attribute__((address_space(3))) unsigned int*)l, 16, 0, 0);
}

// counted barrier: wait N outstanding VMEM + all LDS, then raw s_barrier
#define BARV(N) do {                                                          \
    asm volatile("s_waitcnt vmcnt(" #N ") lgkmcnt(0)" ::: "memory");          \
    __builtin_amdgcn_s_barrier();                                             \
    __builtin_amdgcn_sched_barrier(0);                                        \
  } while (0)

// ---- K0: U fp32 -> fp8(U*16), pad rows [8921,8960) with zeros ----
__global__ __launch_bounds__(256) void cvt_u_kernel(const float* __restrict__ U,
                                                    unsigned char* __restrict__ Ub8) {
  long long idx = ((long long)blockIdx.x * 256 + threadIdx.x) * 8;
  int c = (int)(idx >> 9);
  float f[8];
  if (c < Cn) {
    const float4* p = reinterpret_cast<const float4*>(U + idx);
    float4 a = p[0], b = p[1];
    f[0]=a.x; f[1]=a.y; f[2]=a.z; f[3]=a.w; f[4]=b.x; f[5]=b.y; f[6]=b.z; f[7]=b.w;
  } else {
    #pragma unroll
    for (int i = 0; i < 8; ++i) f[i] = 0.f;
  }
  uint2 v;
  v.x = f2fp8(f[0]*16.f) | (f2fp8(f[1]*16.f) << 8) |
        (f2fp8(f[2]*16.f) << 16) | (f2fp8(f[3]*16.f) << 24);
  v.y = f2fp8(f[4]*16.f) | (f2fp8(f[5]*16.f) << 8) |
        (f2fp8(f[6]*16.f) << 16) | (f2fp8(f[7]*16.f) << 24);
  *reinterpret_cast<uint2*>(Ub8 + idx) = v;
}

// ---- K1: x fp32 -> fp8 xb8[b][l][d] (plain row-major)
// ----     AND bf16 xt3 fragment-tiled (R22-verified): per (b,pair,dq,dt)
// ----     512-ushort block; lane=lg*16+li at lane*8 holds
// ----     x[l=p*32+lg*8+j][d=dq*128+dt*16+li], j=0..7
__global__ __launch_bounds__(256) void cvt_x_kernel(const float* __restrict__ x,
                                                    unsigned char* __restrict__ xb8,
                                                    unsigned short* __restrict__ xt3) {
  __shared__ unsigned short tile[64][72];
  int bid = blockIdx.x;
  int dtb = bid & 7, lt = (bid >> 3) & 31, b = bid >> 8;
  int t = threadIdx.x;
  int r = t >> 2, q = t & 3;                       // row 0..63, col-quarter 0..3
  size_t src_off = (((size_t)b * Ln) + (size_t)(lt*64 + r)) * Dn + dtb*64 + q*16;
  const float4* src = reinterpret_cast<const float4*>(x + src_off);
  unsigned int fb[4];
  #pragma unroll
  for (int i = 0; i < 4; ++i) {
    float4 fv = src[i];
    unsigned int w0 = (unsigned int)f2bf(fv.x) | ((unsigned int)f2bf(fv.y) << 16);
    unsigned int w1 = (unsigned int)f2bf(fv.z) | ((unsigned int)f2bf(fv.w) << 16);
    *reinterpret_cast<uint2*>(&tile[r][q*16 + i*4]) = make_uint2(w0, w1);
    fb[i] = f2fp8(fv.x) | (f2fp8(fv.y) << 8) | (f2fp8(fv.z) << 16) | (f2fp8(fv.w) << 24);
  }
  uint4 f8v; f8v.x = fb[0]; f8v.y = fb[1]; f8v.z = fb[2]; f8v.w = fb[3];
  *reinterpret_cast<uint4*>(xb8 + src_off) = f8v;      // byte addr == elem idx
  __syncthreads();
  int rd = t >> 2, lq = t & 3;                     // d-row 0..63, l-quarter
  unsigned int g[8];
  #pragma unroll
  for (int k = 0; k < 8; ++k) {
    unsigned short a0 = tile[lq*16 + 2*k    ][rd];
    unsigned short a1 = tile[lq*16 + 2*k + 1][rd];
    g[k] = (unsigned int)a0 | ((unsigned int)a1 << 16);
  }
  uint4 o0; o0.x=g[0]; o0.y=g[1]; o0.z=g[2]; o0.w=g[3];   // l+0..7
  uint4 o1; o1.x=g[4]; o1.y=g[5]; o1.z=g[6]; o1.w=g[7];   // l+8..15
  // fragment indices (R22 layout)
  int P   = lt*2 + (lq >> 1);          // pair 0..63
  int lgA = (lq & 1) * 2;              // k-block for o0; o1 = lgA+1
  int d_g = dtb*64 + rd;               // global d
  int dq  = d_g >> 7;
  int dt  = (d_g >> 4) & 7;
  int li  = d_g & 15;
  size_t base = ((((size_t)b * NP + P)*4 + dq)*8 + dt) * 512;   // ushorts
  *reinterpret_cast<uint4*>(xt3 + base + (lgA*16 + li)*8)       = o0;
  *reinterpret_cast<uint4*>(xt3 + base + ((lgA+1)*16 + li)*8)   = o1;
}

// ---- Fused: per WG 64 c-rows x 512 d, stream L in 32-l pairs ----
__global__ __launch_bounds__(512, 2) void fused_kernel(
    const unsigned char* __restrict__ Ub8,
    const unsigned char* __restrict__ xb8,
    const unsigned short* __restrict__ xt3,
    float* __restrict__ out) {
  extern __shared__ unsigned short lds[];
  float* den_s = reinterpret_cast<float*>(lds + DENu);  // [2][64]
  const unsigned char* lb = reinterpret_cast<const unsigned char*>(lds);

  int bid = blockIdx.x;
  int linear = (bid & 7) * (NWGn/8) + (bid >> 3);  // bijective XCD swizzle (2240=8*280)
  int b = linear / NCTn;
  int cblk = linear - b * NCTn;
  int c0 = cblk * CTn;

  int t = threadIdx.x;
  int lane = t & 63;
  int w = t >> 6;          // wave 0..7
  int li = lane & 15;
  int lg = lane >> 4;
  int cg = w & 3;          // G1 role: c-group (16 rows)
  int hf = w >> 2;         // G1 role: l-half of the pair
  int cq = w >> 2;         // G2 role: c-half (32 rows)
  int dq = w & 3;          // G2 role: d-slice (128)

  const unsigned char* xb8p = xb8 + (size_t)b * Ln * Dn;
  const unsigned short* xt3p = xt3 + (size_t)b * NP * 16384;

  // ---- staging lane-consts ----
  int l5 = lane >> 5;                 // xk fp8: row sub-index per issue
  int s16 = lane & 31;                // xk fp8: dest slot16 (16B units)

  // fp8 xk: 2 issues/wave; rows rl = w*4 + 2i + l5 (0..31);
  // slot16 s of row r holds chunk16 s^(r&15): src = ((s16 ^ (rl&15)) * 16)
#define STAGE_XK(P, SLOT)                                                     \
  { _Pragma("unroll")                                                         \
    for (int i = 0; i < 2; ++i) {                                             \
      int rl = w*4 + 2*i + l5;                                                \
      gload16((const unsigned short*)(xb8p +                                  \
                  (size_t)((P)*32 + rl) * 512 +                               \
                  (size_t)(((s16 ^ (rl & 15)) * 16))),                        \
              lds + XKu(SLOT) + (w*4 + 2*i) * 256);                           \
    } }

  // U fp8 fragments for MX-scaled 16x16x128: rows c0 + cg*16 + li;
  // step s needs 32 B/lane at K = s*128 + lg*32
  i32x8 us[4];
  {
    const unsigned char* up8 = Ub8 + (size_t)(c0 + cg*16 + li) * 512;
    #pragma unroll
    for (int s = 0; s < 4; ++s) {
      i32x4 qa = *reinterpret_cast<const i32x4*>(up8 + s*128 + lg*32);
      i32x4 qb = *reinterpret_cast<const i32x4*>(up8 + s*128 + lg*32 + 16);
      us[s] = __builtin_shufflevector(qa, qb, 0, 1, 2, 3, 4, 5, 6, 7);
    }
  }
  __builtin_amdgcn_sched_barrier(0);   // pin U loads BEFORE staging (vmcnt ledger)

  STAGE_XK(0, 0);

  f32x4 acc[2][8];   // c = cq*32 + rr*16 + lg*4 + j,  d = dq*128 + dt*16 + li
  #pragma unroll
  for (int i = 0; i < 2; ++i)
    #pragma unroll
    for (int j = 0; j < 8; ++j) acc[i][j] = (f32x4){0.f, 0.f, 0.f, 0.f};
  float dsum[4];
  #pragma unroll
  for (int j = 0; j < 4; ++j) dsum[j] = 0.f;

  bf16x8 fr[8];      // G2 B-fragments (pair p), live across the barrier

  // G2 lane-const offset into P
  int pboff = ((lg >> 1) ? 1536 : 0) + (cq*32 + li)*P_S + (lg & 1)*8;

  BARV(0);   // U + XK(0) landed

  for (int p = 0; p < NP; ++p) {
    // ---- stage XK(p+1), 1-ahead dbuf; MUST issue before fr (ledger) ----
    if (p + 1 < NP) { STAGE_XK(p + 1, (p + 1) & 1); }
    __builtin_amdgcn_sched_barrier(0);

    // ---- G1(p): MX-scaled fp8 (4 K-steps of 128) from XK slot p&1 ----
    f32x4 a0 = (f32x4){0.f, 0.f, 0.f, 0.f};
    {
      const unsigned char* x0 = lb + (p & 1)*16384 + hf*8192 + li*512;
      __builtin_amdgcn_s_setprio(1);
      #pragma unroll
      for (int s = 0; s < 4; ++s) {
        int cp = s*8 + lg*2;                   // base chunk16 (16B units)
        int o0 = ((cp    ) ^ li) * 16;
        int o1 = ((cp + 1) ^ li) * 16;
        i32x4 qa0 = *reinterpret_cast<const i32x4*>(x0 + o0);
        i32x4 qb0 = *reinterpret_cast<const i32x4*>(x0 + o1);
        i32x8 bv0 = __builtin_shufflevector(qa0, qb0, 0, 1, 2, 3, 4, 5, 6, 7);
        a0 = __builtin_amdgcn_mfma_scale_f32_16x16x128_f8f6f4(
                 us[s], bv0, a0, 0, 0, 0, 0x7F7F7F7F, 0, 0x7F7F7F7F);
      }
      __builtin_amdgcn_s_setprio(0);
    }

    // ---- G2(p-1): bf16 GEMM2 from fr regs + P slot (p-1)&1 ----
    if (p > 0) {
      const unsigned short* pws = lds + Pu((p - 1) & 1) + pboff;
      bf16x8 pa0 = *reinterpret_cast<const bf16x8*>(pws);
      bf16x8 pa1 = *reinterpret_cast<const bf16x8*>(pws + 16*P_S);
      __builtin_amdgcn_s_setprio(1);
      #pragma unroll
      for (int dt = 0; dt < 8; ++dt) {
        acc[0][dt] = __builtin_amdgcn_mfma_f32_16x16x32_bf16(
            pa0, fr[dt], acc[0][dt], 0, 0, 0);
        acc[1][dt] = __builtin_amdgcn_mfma_f32_16x16x32_bf16(
            pa1, fr[dt], acc[1][dt], 0, 0, 0);
      }
      __builtin_amdgcn_s_setprio(0);
    }
    __builtin_amdgcn_sched_barrier(0);   // keep fr(p) loads BELOW G2(p-1)

    // ---- load fr(p): 8 x dwordx4 from xt3 (consumed NEXT phase) ----
    {
      const unsigned short* fb = xt3p + (size_t)p*16384 + dq*4096 + lane*8;
      #pragma unroll
      for (int dt = 0; dt < 8; ++dt)
        fr[dt] = *reinterpret_cast<const bf16x8*>(fb + dt*512);
    }

    // ---- softmax-finish(p) -> P slot p&1 (half hf, rows cg*16+...) ----
    {
      unsigned short* pw = lds + Pu(p & 1) + hf*1536;
      #pragma unroll
      for (int j = 0; j < 4; ++j) {
        float pv = __expf(a0[j] * 0.0625f);   // undo U*16
        dsum[j] += pv;
        pw[(cg*16 + lg*4 + j)*P_S + li] = f2bf(pv);
      }
    }

    // ---- single barrier per pair: drains XK(p+1), keeps fr(p) in flight ----
    BARV(8);
  }

  // ---- post-loop G2(NP-1): fr(NP-1) + P slot (NP-1)&1 = 1 ----
  {
    const unsigned short* pws = lds + Pu(1) + pboff;
    bf16x8 pa0 = *reinterpret_cast<const bf16x8*>(pws);
    bf16x8 pa1 = *reinterpret_cast<const bf16x8*>(pws + 16*P_S);
    __builtin_amdgcn_s_setprio(1);
    #pragma unroll
    for (int dt = 0; dt < 8; ++dt) {
      acc[0][dt] = __builtin_amdgcn_mfma_f32_16x16x32_bf16(
          pa0, fr[dt], acc[0][dt], 0, 0, 0);
      acc[1][dt] = __builtin_amdgcn_mfma_f32_16x16x32_bf16(
          pa1, fr[dt], acc[1][dt], 0, 0, 0);
    }
    __builtin_amdgcn_s_setprio(0);
  }

  // denom: reduce over 16 l-lanes (li bits); wave (cg,hf) owns its partial
  #pragma unroll
  for (int m = 1; m < 16; m <<= 1)
    #pragma unroll
    for (int j = 0; j < 4; ++j)
      dsum[j] += __shfl_xor(dsum[j], m, 64);
  if (li == 0) {
    #pragma unroll
    for (int j = 0; j < 4; ++j)
      den_s[hf*64 + cg*16 + lg*4 + j] = dsum[j];
  }
  __syncthreads();   // den partials ready; all G2 LDS reads done

  // epilogue: divide (sum both hf partials), per-wave LDS transpose, stores
  {
    float* er = reinterpret_cast<float*>(lds) + w * (16 * ER_S);
    int csub0 = lane >> 5;          // 0..1
    int dcol = (lane & 31) * 4;
    #pragma unroll
    for (int rr = 0; rr < 2; ++rr) {
      __syncthreads();   // er region free
      #pragma unroll
      for (int j = 0; j < 4; ++j) {
        int row = lg*4 + j;
        int c64 = cq*32 + rr*16 + row;
        float inv = 1.0f / (den_s[c64] + den_s[64 + c64]);
        #pragma unroll
        for (int dt = 0; dt < 8; ++dt)
          er[row*ER_S + dt*16 + li] = acc[rr][dt][j] * inv;
      }
      __syncthreads();   // er ready
      #pragma unroll
      for (int it = 0; it < 8; ++it) {
        int crow = it*2 + csub0;
        float4 v = *reinterpret_cast<const float4*>(&er[crow*ER_S + dcol]);
        int c = c0 + cq*32 + rr*16 + crow;
        if (c < Cn)
          *reinterpret_cast<float4*>(out + ((size_t)b*Cn + c)*Dn + dq*128 + dcol) = v;
      }
    }
  }
}

extern "C" void kernel_launch(void* const* d_in, const int* in_sizes, int n_in,
                              void* d_out, int out_size, void* d_ws, size_t ws_size,
                              hipStream_t stream) {
  const float* x = (const float*)d_in[0];
  const float* U = (const float*)d_in[1];
  float* out = (float*)d_out;

  // ws layout: Ub8[8960*512 B] | xb8[16*2048*512 B] | xt3 bf16[16*64*16384]
  unsigned char* Ub8 = (unsigned char*)d_ws;
  unsigned char* xb8 = Ub8 + (size_t)CPn * Dn;
  unsigned short* xt3 = (unsigned short*)(xb8 + (size_t)Bn * Ln * Dn);

  hipFuncSetAttribute((const void*)fused_kernel,
                      hipFuncAttributeMaxDynamicSharedMemorySize, LDS_BYTES);

  cvt_u_kernel<<<(CPn*Dn)/(256*8), 256, 0, stream>>>(U, Ub8);
  cvt_x_kernel<<<Bn*32*8, 256, 0, stream>>>(x, xb8, xt3);
  fused_kernel<<<NWGn, 512, LDS_BYTES, stream>>>(Ub8, xb8, xt3, out);
}